// Round 1
// baseline (1103.286 us; speedup 1.0000x reference)
//
#include <hip/hip_runtime.h>

#define N_NODES 50000
#define N_EDGES 600000
#define DFEAT   128

// ---------------- degree ----------------
__global__ void sage_deg_kernel(const int* __restrict__ dst, float* __restrict__ deg, int nE) {
    int e = blockIdx.x * blockDim.x + threadIdx.x;
    if (e < nE) atomicAdd(&deg[dst[e]], 1.0f);
}

__global__ void sage_inv_kernel(float* __restrict__ deg, int n) {
    int i = blockIdx.x * blockDim.x + threadIdx.x;
    if (i < n) deg[i] = 1.0f / fmaxf(deg[i], 1.0f);
}

// ---------------- scatter-add of raw features (d=128) ----------------
// 2 edges per 256-thread block: coalesced 512B read of h[src], coalesced
// atomic row-add into agg[dst].
__global__ void sage_scatter_kernel(const float* __restrict__ h,
                                    const int* __restrict__ src,
                                    const int* __restrict__ dst,
                                    float* __restrict__ agg, int nE) {
    int e = blockIdx.x * 2 + (threadIdx.x >> 7);
    int f = threadIdx.x & 127;
    if (e < nE) {
        int s = src[e];
        int d = dst[e];
        atomicAdd(&agg[(long)d * DFEAT + f], h[(long)s * DFEAT + f]);
    }
}

// ---------------- fused dual-matmul + bias + relu ----------------
// out[n][j] = act( sum_k h[n][k]*Ws[k][j] + (agg[n][k]*invdeg[n])*Wn[k][j] + b[j] )
// Tile: 64 rows per block; each thread: CPT=4 cols x RPT rows (32 or 16 accs).
// h/agg tiles staged in LDS (stride 132 floats -> float4-aligned, rows 8 apart
// land on same bank -> only 2-way broadcast conflict, free on gfx950).
template<int OUTD, bool RELU>
__global__ __launch_bounds__(256) void sage_mm_kernel(
        const float* __restrict__ h, const float* __restrict__ agg,
        const float* __restrict__ invdeg,
        const float* __restrict__ Ws, const float* __restrict__ Wn,
        const float* __restrict__ bias,
        float* __restrict__ out, int nrows)
{
    constexpr int K   = 128;
    constexpr int CPT = 4;
    constexpr int CG  = OUTD / CPT;      // 32 (d=128) or 16 (d=64)
    constexpr int RG  = 256 / CG;        // 8 or 16
    constexpr int RPT = (OUTD == 128) ? 8 : 4;
    constexpr int TILE_R = RG * RPT;     // 64 both
    constexpr int LDK = K + 4;           // padded row stride (floats), keeps 16B align

    __shared__ float hs[TILE_R * LDK];
    __shared__ float as[TILE_R * LDK];

    const int t  = threadIdx.x;
    const int cg = t % CG;
    const int rg = t / CG;
    const int rowbase = blockIdx.x * TILE_R;

    // ---- stage tiles (h, and agg scaled by invdeg) ----
    #pragma unroll 4
    for (int idx = t; idx < TILE_R * (K / 4); idx += 256) {
        int r  = idx >> 5;          // / (K/4)
        int c4 = idx & 31;
        int grow = rowbase + r;
        float4 hv = make_float4(0.f, 0.f, 0.f, 0.f);
        float4 av = make_float4(0.f, 0.f, 0.f, 0.f);
        if (grow < nrows) {
            hv = *(const float4*)(h + (long)grow * K + c4 * 4);
            float s = invdeg[grow];
            float4 a = *(const float4*)(agg + (long)grow * K + c4 * 4);
            av = make_float4(a.x * s, a.y * s, a.z * s, a.w * s);
        }
        *(float4*)(hs + r * LDK + c4 * 4) = hv;
        *(float4*)(as + r * LDK + c4 * 4) = av;
    }
    __syncthreads();

    float acc[RPT][CPT] = {};

    for (int k4 = 0; k4 < K; k4 += 4) {
        float4 wsv[4], wnv[4];
        #pragma unroll
        for (int kk = 0; kk < 4; kk++) {
            wsv[kk] = *(const float4*)(Ws + (long)(k4 + kk) * OUTD + cg * 4);
            wnv[kk] = *(const float4*)(Wn + (long)(k4 + kk) * OUTD + cg * 4);
        }
        #pragma unroll
        for (int i = 0; i < RPT; i++) {
            int r = rg * RPT + i;
            float4 hv = *(const float4*)(hs + r * LDK + k4);
            float4 av = *(const float4*)(as + r * LDK + k4);
            const float* hp = (const float*)&hv;
            const float* ap = (const float*)&av;
            #pragma unroll
            for (int kk = 0; kk < 4; kk++) {
                const float* wsp = (const float*)&wsv[kk];
                const float* wnp = (const float*)&wnv[kk];
                #pragma unroll
                for (int c = 0; c < CPT; c++) {
                    acc[i][c] += hp[kk] * wsp[c] + ap[kk] * wnp[c];
                }
            }
        }
    }

    float4 bv = *(const float4*)(bias + cg * 4);
    const float* bp = (const float*)&bv;
    #pragma unroll
    for (int i = 0; i < RPT; i++) {
        int grow = rowbase + rg * RPT + i;
        if (grow < nrows) {
            float o[CPT];
            #pragma unroll
            for (int c = 0; c < CPT; c++) {
                o[c] = acc[i][c] + bp[c];
                if (RELU) o[c] = fmaxf(o[c], 0.f);
            }
            *(float4*)(out + (long)grow * OUTD + cg * 4) =
                make_float4(o[0], o[1], o[2], o[3]);
        }
    }
}

extern "C" void kernel_launch(void* const* d_in, const int* in_sizes, int n_in,
                              void* d_out, int out_size, void* d_ws, size_t ws_size,
                              hipStream_t stream) {
    const float* x   = (const float*)d_in[0];
    const int*   ei  = (const int*)d_in[1];      // int32 per harness convention
    const float* Ws0 = (const float*)d_in[2];
    const float* Wn0 = (const float*)d_in[3];
    const float* b0  = (const float*)d_in[4];
    const float* Ws1 = (const float*)d_in[5];
    const float* Wn1 = (const float*)d_in[6];
    const float* b1  = (const float*)d_in[7];
    const float* Ws2 = (const float*)d_in[8];
    const float* Wn2 = (const float*)d_in[9];
    const float* b2  = (const float*)d_in[10];
    float* out = (float*)d_out;

    const int* src = ei;
    const int* dst = ei + N_EDGES;

    float* wsf    = (float*)d_ws;
    float* invdeg = wsf;                              // 50000 floats
    float* agg    = wsf + 50176;                      // 6.4M floats
    float* h0     = agg + (long)N_NODES * DFEAT;      // 6.4M floats
    float* h1     = h0  + (long)N_NODES * DFEAT;      // 6.4M floats

    // degrees -> inv_deg (in place)
    hipMemsetAsync(invdeg, 0, N_NODES * sizeof(float), stream);
    sage_deg_kernel<<<(N_EDGES + 255) / 256, 256, 0, stream>>>(dst, invdeg, N_EDGES);
    sage_inv_kernel<<<(N_NODES + 255) / 256, 256, 0, stream>>>(invdeg, N_NODES);

    const int scatter_blocks = (N_EDGES + 1) / 2;
    const int mm_blocks = (N_NODES + 63) / 64;

    // ---- layer 0 ----
    hipMemsetAsync(agg, 0, (size_t)N_NODES * DFEAT * sizeof(float), stream);
    sage_scatter_kernel<<<scatter_blocks, 256, 0, stream>>>(x, src, dst, agg, N_EDGES);
    sage_mm_kernel<128, true><<<mm_blocks, 256, 0, stream>>>(
        x, agg, invdeg, Ws0, Wn0, b0, h0, N_NODES);

    // ---- layer 1 ----
    hipMemsetAsync(agg, 0, (size_t)N_NODES * DFEAT * sizeof(float), stream);
    sage_scatter_kernel<<<scatter_blocks, 256, 0, stream>>>(h0, src, dst, agg, N_EDGES);
    sage_mm_kernel<128, true><<<mm_blocks, 256, 0, stream>>>(
        h0, agg, invdeg, Ws1, Wn1, b1, h1, N_NODES);

    // ---- layer 2 ----
    hipMemsetAsync(agg, 0, (size_t)N_NODES * DFEAT * sizeof(float), stream);
    sage_scatter_kernel<<<scatter_blocks, 256, 0, stream>>>(h1, src, dst, agg, N_EDGES);
    sage_mm_kernel<64, false><<<mm_blocks, 256, 0, stream>>>(
        h1, agg, invdeg, Ws2, Wn2, b2, out, N_NODES);
}

// Round 2
// 593.179 us; speedup vs baseline: 1.8600x; 1.8600x over previous
//
#include <hip/hip_runtime.h>

#define N_NODES 50000
#define N_EDGES 600000
#define DFEAT   128

// ---------------- CSR build step 1: int histogram of dst ----------------
__global__ void sage_hist_kernel(const int* __restrict__ dst, int* __restrict__ cnt, int nE) {
    int e = blockIdx.x * blockDim.x + threadIdx.x;
    if (e < nE) atomicAdd(&cnt[dst[e]], 1);
}

// ---------------- CSR build step 2: single-block exclusive scan ----------------
// Also emits invdeg = 1/max(deg,1).
__global__ __launch_bounds__(1024) void sage_scan_kernel(
        const int* __restrict__ cnt, int* __restrict__ row_ptr,
        float* __restrict__ invdeg, int n) {
    __shared__ int buf[1024];
    __shared__ int carry_s;
    const int t = threadIdx.x;
    if (t == 0) carry_s = 0;
    __syncthreads();
    for (int base = 0; base < n; base += 1024) {
        int i = base + t;
        int v = (i < n) ? cnt[i] : 0;
        if (i < n) invdeg[i] = 1.0f / fmaxf((float)v, 1.0f);
        buf[t] = v;
        __syncthreads();
        #pragma unroll
        for (int off = 1; off < 1024; off <<= 1) {
            int x = (t >= off) ? buf[t - off] : 0;
            __syncthreads();
            buf[t] += x;
            __syncthreads();
        }
        int incl = buf[t];
        int carry = carry_s;
        if (i < n) row_ptr[i] = carry + incl - v;   // exclusive
        __syncthreads();
        if (t == 1023) carry_s = carry + incl;
        __syncthreads();
    }
    if (t == 0) row_ptr[n] = carry_s;
}

// ---------------- CSR build step 3: fill sorted_src via cursor ----------------
__global__ void sage_fill_kernel(const int* __restrict__ src, const int* __restrict__ dst,
                                 int* __restrict__ cursor, int* __restrict__ sorted_src, int nE) {
    int e = blockIdx.x * blockDim.x + threadIdx.x;
    if (e < nE) {
        int p = atomicAdd(&cursor[dst[e]], 1);
        sorted_src[p] = src[e];
    }
}

// ---------------- pull-based mean aggregation ----------------
// 2 nodes per 256-thread block; thread f=tid&127 owns feature f.
// Coalesced 512B row gathers; 4 accumulators for load ILP; writes mean directly.
__global__ __launch_bounds__(256) void sage_gather_kernel(
        const float* __restrict__ h, const int* __restrict__ row_ptr,
        const int* __restrict__ sorted_src, const float* __restrict__ invdeg,
        float* __restrict__ mean, int nNodes)
{
    int node = blockIdx.x * 2 + (threadIdx.x >> 7);
    int f = threadIdx.x & 127;
    if (node >= nNodes) return;
    const int beg = row_ptr[node];
    const int end = row_ptr[node + 1];
    float a0 = 0.f, a1 = 0.f, a2 = 0.f, a3 = 0.f;
    int e = beg;
    for (; e + 4 <= end; e += 4) {
        int s0 = sorted_src[e];
        int s1 = sorted_src[e + 1];
        int s2 = sorted_src[e + 2];
        int s3 = sorted_src[e + 3];
        a0 += h[(long)s0 * DFEAT + f];
        a1 += h[(long)s1 * DFEAT + f];
        a2 += h[(long)s2 * DFEAT + f];
        a3 += h[(long)s3 * DFEAT + f];
    }
    for (; e < end; e++) a0 += h[(long)sorted_src[e] * DFEAT + f];
    mean[(long)node * DFEAT + f] = (a0 + a1 + a2 + a3) * invdeg[node];
}

// ---------------- fused dual-matmul + bias + relu ----------------
// out[n][j] = act( sum_k h[n][k]*Ws[k][j] + mean[n][k]*Wn[k][j] + b[j] )
template<int OUTD, bool RELU>
__global__ __launch_bounds__(256) void sage_mm_kernel(
        const float* __restrict__ h, const float* __restrict__ mean,
        const float* __restrict__ Ws, const float* __restrict__ Wn,
        const float* __restrict__ bias,
        float* __restrict__ out, int nrows)
{
    constexpr int K   = 128;
    constexpr int CPT = 4;
    constexpr int CG  = OUTD / CPT;      // 32 (d=128) or 16 (d=64)
    constexpr int RG  = 256 / CG;        // 8 or 16
    constexpr int RPT = (OUTD == 128) ? 8 : 4;
    constexpr int TILE_R = RG * RPT;     // 64 both
    constexpr int LDK = K + 4;           // padded row stride (floats), keeps 16B align

    __shared__ float hs[TILE_R * LDK];
    __shared__ float as[TILE_R * LDK];

    const int t  = threadIdx.x;
    const int cg = t % CG;
    const int rg = t / CG;
    const int rowbase = blockIdx.x * TILE_R;

    // ---- stage tiles ----
    #pragma unroll 4
    for (int idx = t; idx < TILE_R * (K / 4); idx += 256) {
        int r  = idx >> 5;          // / (K/4)
        int c4 = idx & 31;
        int grow = rowbase + r;
        float4 hv = make_float4(0.f, 0.f, 0.f, 0.f);
        float4 av = make_float4(0.f, 0.f, 0.f, 0.f);
        if (grow < nrows) {
            hv = *(const float4*)(h + (long)grow * K + c4 * 4);
            av = *(const float4*)(mean + (long)grow * K + c4 * 4);
        }
        *(float4*)(hs + r * LDK + c4 * 4) = hv;
        *(float4*)(as + r * LDK + c4 * 4) = av;
    }
    __syncthreads();

    float acc[RPT][CPT] = {};

    for (int k4 = 0; k4 < K; k4 += 4) {
        float4 wsv[4], wnv[4];
        #pragma unroll
        for (int kk = 0; kk < 4; kk++) {
            wsv[kk] = *(const float4*)(Ws + (long)(k4 + kk) * OUTD + cg * 4);
            wnv[kk] = *(const float4*)(Wn + (long)(k4 + kk) * OUTD + cg * 4);
        }
        #pragma unroll
        for (int i = 0; i < RPT; i++) {
            int r = rg * RPT + i;
            float4 hv = *(const float4*)(hs + r * LDK + k4);
            float4 av = *(const float4*)(as + r * LDK + k4);
            const float* hp = (const float*)&hv;
            const float* ap = (const float*)&av;
            #pragma unroll
            for (int kk = 0; kk < 4; kk++) {
                const float* wsp = (const float*)&wsv[kk];
                const float* wnp = (const float*)&wnv[kk];
                #pragma unroll
                for (int c = 0; c < CPT; c++) {
                    acc[i][c] += hp[kk] * wsp[c] + ap[kk] * wnp[c];
                }
            }
        }
    }

    float4 bv = *(const float4*)(bias + cg * 4);
    const float* bp = (const float*)&bv;
    #pragma unroll
    for (int i = 0; i < RPT; i++) {
        int grow = rowbase + rg * RPT + i;
        if (grow < nrows) {
            float o[CPT];
            #pragma unroll
            for (int c = 0; c < CPT; c++) {
                o[c] = acc[i][c] + bp[c];
                if (RELU) o[c] = fmaxf(o[c], 0.f);
            }
            *(float4*)(out + (long)grow * OUTD + cg * 4) =
                make_float4(o[0], o[1], o[2], o[3]);
        }
    }
}

extern "C" void kernel_launch(void* const* d_in, const int* in_sizes, int n_in,
                              void* d_out, int out_size, void* d_ws, size_t ws_size,
                              hipStream_t stream) {
    const float* x   = (const float*)d_in[0];
    const int*   ei  = (const int*)d_in[1];
    const float* Ws0 = (const float*)d_in[2];
    const float* Wn0 = (const float*)d_in[3];
    const float* b0  = (const float*)d_in[4];
    const float* Ws1 = (const float*)d_in[5];
    const float* Wn1 = (const float*)d_in[6];
    const float* b1  = (const float*)d_in[7];
    const float* Ws2 = (const float*)d_in[8];
    const float* Wn2 = (const float*)d_in[9];
    const float* b2  = (const float*)d_in[10];
    float* out = (float*)d_out;

    const int* src = ei;
    const int* dst = ei + N_EDGES;

    // ---- workspace layout (floats/ints, 256-element aligned) ----
    char* ws = (char*)d_ws;
    float* invdeg     = (float*)ws;                          ws += 50176 * 4;
    int*   cnt        = (int*)ws;                            ws += 50176 * 4;
    int*   row_ptr    = (int*)ws;                            ws += 50432 * 4;
    int*   cursor     = (int*)ws;                            ws += 50432 * 4;
    int*   sorted_src = (int*)ws;                            ws += 600064 * 4;
    float* mean       = (float*)ws;                          ws += (long)N_NODES * DFEAT * 4;
    float* h0         = (float*)ws;                          ws += (long)N_NODES * DFEAT * 4;
    float* h1         = (float*)ws;

    // ---- CSR build ----
    hipMemsetAsync(cnt, 0, 50176 * sizeof(int), stream);
    sage_hist_kernel<<<(N_EDGES + 255) / 256, 256, 0, stream>>>(dst, cnt, N_EDGES);
    sage_scan_kernel<<<1, 1024, 0, stream>>>(cnt, row_ptr, invdeg, N_NODES);
    hipMemcpyAsync(cursor, row_ptr, (N_NODES + 1) * sizeof(int),
                   hipMemcpyDeviceToDevice, stream);
    sage_fill_kernel<<<(N_EDGES + 255) / 256, 256, 0, stream>>>(
        src, dst, cursor, sorted_src, N_EDGES);

    const int gather_blocks = (N_NODES + 1) / 2;
    const int mm_blocks = (N_NODES + 63) / 64;

    // ---- layer 0 ----
    sage_gather_kernel<<<gather_blocks, 256, 0, stream>>>(
        x, row_ptr, sorted_src, invdeg, mean, N_NODES);
    sage_mm_kernel<128, true><<<mm_blocks, 256, 0, stream>>>(
        x, mean, Ws0, Wn0, b0, h0, N_NODES);

    // ---- layer 1 ----
    sage_gather_kernel<<<gather_blocks, 256, 0, stream>>>(
        h0, row_ptr, sorted_src, invdeg, mean, N_NODES);
    sage_mm_kernel<128, true><<<mm_blocks, 256, 0, stream>>>(
        h0, mean, Ws1, Wn1, b1, h1, N_NODES);

    // ---- layer 2 ----
    sage_gather_kernel<<<gather_blocks, 256, 0, stream>>>(
        h1, row_ptr, sorted_src, invdeg, mean, N_NODES);
    sage_mm_kernel<64, false><<<mm_blocks, 256, 0, stream>>>(
        h1, mean, Ws2, Wn2, b2, out, N_NODES);
}

// Round 3
// 501.061 us; speedup vs baseline: 2.2019x; 1.1838x over previous
//
#include <hip/hip_runtime.h>

#define N_NODES 50000
#define N_EDGES 600000
#define DFEAT   128
#define SCAN_NB ((N_NODES + 255) / 256)   // 196 blocks

// ---------------- CSR build step 1: int histogram of dst ----------------
__global__ void sage_hist_kernel(const int* __restrict__ dst, int* __restrict__ cnt, int nE) {
    int e = blockIdx.x * blockDim.x + threadIdx.x;
    if (e < nE) atomicAdd(&cnt[dst[e]], 1);
}

// ---------------- CSR build step 2a: per-block sums (256 counts/block) ----------------
__global__ __launch_bounds__(256) void sage_bsum_kernel(
        const int* __restrict__ cnt, int* __restrict__ bsum, int n) {
    int i = blockIdx.x * 256 + threadIdx.x;
    int v = (i < n) ? cnt[i] : 0;
    #pragma unroll
    for (int off = 32; off > 0; off >>= 1) v += __shfl_down(v, off, 64);
    __shared__ int ws[4];
    if ((threadIdx.x & 63) == 0) ws[threadIdx.x >> 6] = v;
    __syncthreads();
    if (threadIdx.x == 0) bsum[blockIdx.x] = ws[0] + ws[1] + ws[2] + ws[3];
}

// ---------------- CSR build step 2b: exclusive scan of block sums (nb<=256) ----------------
__global__ __launch_bounds__(256) void sage_bscan_kernel(int* __restrict__ bsum, int nb) {
    int t = threadIdx.x;
    int v = (t < nb) ? bsum[t] : 0;
    int lane = t & 63, wid = t >> 6;
    int incl = v;
    #pragma unroll
    for (int off = 1; off < 64; off <<= 1) {
        int y = __shfl_up(incl, off, 64);
        if (lane >= off) incl += y;
    }
    __shared__ int ws[4];
    if (lane == 63) ws[wid] = incl;
    __syncthreads();
    int wpre = 0;
    for (int w = 0; w < wid; w++) wpre += ws[w];
    if (t < nb) bsum[t] = wpre + incl - v;   // exclusive
}

// ---------------- CSR build step 2c: per-block scan + offset -> row_ptr/cursor/invdeg ----------
__global__ __launch_bounds__(256) void sage_scan2_kernel(
        const int* __restrict__ cnt, const int* __restrict__ bscan,
        int* __restrict__ row_ptr, int* __restrict__ cursor,
        float* __restrict__ invdeg, int n) {
    int i = blockIdx.x * 256 + threadIdx.x;
    int v = (i < n) ? cnt[i] : 0;
    int lane = threadIdx.x & 63, wid = threadIdx.x >> 6;
    int incl = v;
    #pragma unroll
    for (int off = 1; off < 64; off <<= 1) {
        int y = __shfl_up(incl, off, 64);
        if (lane >= off) incl += y;
    }
    __shared__ int ws[4];
    if (lane == 63) ws[wid] = incl;
    __syncthreads();
    int wpre = 0;
    for (int w = 0; w < wid; w++) wpre += ws[w];
    int excl = bscan[blockIdx.x] + wpre + incl - v;
    if (i < n) {
        row_ptr[i] = excl;
        cursor[i]  = excl;
        invdeg[i]  = 1.0f / fmaxf((float)v, 1.0f);
    }
    if (i == n - 1) row_ptr[n] = excl + v;
}

// ---------------- CSR build step 3: fill sorted_src via cursor ----------------
__global__ void sage_fill_kernel(const int* __restrict__ src, const int* __restrict__ dst,
                                 int* __restrict__ cursor, int* __restrict__ sorted_src, int nE) {
    int e = blockIdx.x * blockDim.x + threadIdx.x;
    if (e < nE) {
        int p = atomicAdd(&cursor[dst[e]], 1);
        sorted_src[p] = src[e];
    }
}

// ---------------- pull-based mean aggregation ----------------
__global__ __launch_bounds__(256) void sage_gather_kernel(
        const float* __restrict__ h, const int* __restrict__ row_ptr,
        const int* __restrict__ sorted_src, const float* __restrict__ invdeg,
        float* __restrict__ mean, int nNodes)
{
    int node = blockIdx.x * 2 + (threadIdx.x >> 7);
    int f = threadIdx.x & 127;
    if (node >= nNodes) return;
    const int beg = row_ptr[node];
    const int end = row_ptr[node + 1];
    float a0 = 0.f, a1 = 0.f, a2 = 0.f, a3 = 0.f;
    int e = beg;
    for (; e + 4 <= end; e += 4) {
        int s0 = sorted_src[e];
        int s1 = sorted_src[e + 1];
        int s2 = sorted_src[e + 2];
        int s3 = sorted_src[e + 3];
        a0 += h[(long)s0 * DFEAT + f];
        a1 += h[(long)s1 * DFEAT + f];
        a2 += h[(long)s2 * DFEAT + f];
        a3 += h[(long)s3 * DFEAT + f];
    }
    for (; e < end; e++) a0 += h[(long)sorted_src[e] * DFEAT + f];
    mean[(long)node * DFEAT + f] = (a0 + a1 + a2 + a3) * invdeg[node];
}

// ---------------- fused dual-matmul + bias + relu ----------------
template<int OUTD, bool RELU>
__global__ __launch_bounds__(256) void sage_mm_kernel(
        const float* __restrict__ h, const float* __restrict__ mean,
        const float* __restrict__ Ws, const float* __restrict__ Wn,
        const float* __restrict__ bias,
        float* __restrict__ out, int nrows)
{
    constexpr int K   = 128;
    constexpr int CPT = 4;
    constexpr int CG  = OUTD / CPT;      // 32 (d=128) or 16 (d=64)
    constexpr int RG  = 256 / CG;        // 8 or 16
    constexpr int RPT = (OUTD == 128) ? 8 : 4;
    constexpr int TILE_R = RG * RPT;     // 64 both
    constexpr int LDK = K + 4;

    __shared__ float hs[TILE_R * LDK];
    __shared__ float as[TILE_R * LDK];

    const int t  = threadIdx.x;
    const int cg = t % CG;
    const int rg = t / CG;
    const int rowbase = blockIdx.x * TILE_R;

    #pragma unroll 4
    for (int idx = t; idx < TILE_R * (K / 4); idx += 256) {
        int r  = idx >> 5;
        int c4 = idx & 31;
        int grow = rowbase + r;
        float4 hv = make_float4(0.f, 0.f, 0.f, 0.f);
        float4 av = make_float4(0.f, 0.f, 0.f, 0.f);
        if (grow < nrows) {
            hv = *(const float4*)(h + (long)grow * K + c4 * 4);
            av = *(const float4*)(mean + (long)grow * K + c4 * 4);
        }
        *(float4*)(hs + r * LDK + c4 * 4) = hv;
        *(float4*)(as + r * LDK + c4 * 4) = av;
    }
    __syncthreads();

    float acc[RPT][CPT] = {};

    for (int k4 = 0; k4 < K; k4 += 4) {
        float4 wsv[4], wnv[4];
        #pragma unroll
        for (int kk = 0; kk < 4; kk++) {
            wsv[kk] = *(const float4*)(Ws + (long)(k4 + kk) * OUTD + cg * 4);
            wnv[kk] = *(const float4*)(Wn + (long)(k4 + kk) * OUTD + cg * 4);
        }
        #pragma unroll
        for (int i = 0; i < RPT; i++) {
            int r = rg * RPT + i;
            float4 hv = *(const float4*)(hs + r * LDK + k4);
            float4 av = *(const float4*)(as + r * LDK + k4);
            const float* hp = (const float*)&hv;
            const float* ap = (const float*)&av;
            #pragma unroll
            for (int kk = 0; kk < 4; kk++) {
                const float* wsp = (const float*)&wsv[kk];
                const float* wnp = (const float*)&wnv[kk];
                #pragma unroll
                for (int c = 0; c < CPT; c++) {
                    acc[i][c] += hp[kk] * wsp[c] + ap[kk] * wnp[c];
                }
            }
        }
    }

    float4 bv = *(const float4*)(bias + cg * 4);
    const float* bp = (const float*)&bv;
    #pragma unroll
    for (int i = 0; i < RPT; i++) {
        int grow = rowbase + rg * RPT + i;
        if (grow < nrows) {
            float o[CPT];
            #pragma unroll
            for (int c = 0; c < CPT; c++) {
                o[c] = acc[i][c] + bp[c];
                if (RELU) o[c] = fmaxf(o[c], 0.f);
            }
            *(float4*)(out + (long)grow * OUTD + cg * 4) =
                make_float4(o[0], o[1], o[2], o[3]);
        }
    }
}

extern "C" void kernel_launch(void* const* d_in, const int* in_sizes, int n_in,
                              void* d_out, int out_size, void* d_ws, size_t ws_size,
                              hipStream_t stream) {
    const float* x   = (const float*)d_in[0];
    const int*   ei  = (const int*)d_in[1];
    const float* Ws0 = (const float*)d_in[2];
    const float* Wn0 = (const float*)d_in[3];
    const float* b0  = (const float*)d_in[4];
    const float* Ws1 = (const float*)d_in[5];
    const float* Wn1 = (const float*)d_in[6];
    const float* b1  = (const float*)d_in[7];
    const float* Ws2 = (const float*)d_in[8];
    const float* Wn2 = (const float*)d_in[9];
    const float* b2  = (const float*)d_in[10];
    float* out = (float*)d_out;

    const int* src = ei;
    const int* dst = ei + N_EDGES;

    // ---- workspace layout ----
    char* ws = (char*)d_ws;
    float* invdeg     = (float*)ws;                          ws += 50176 * 4;
    int*   cnt        = (int*)ws;                            ws += 50176 * 4;
    int*   row_ptr    = (int*)ws;                            ws += 50432 * 4;
    int*   cursor     = (int*)ws;                            ws += 50432 * 4;
    int*   bsum       = (int*)ws;                            ws += 256 * 4;
    int*   sorted_src = (int*)ws;                            ws += 600064 * 4;
    float* mean       = (float*)ws;                          ws += (long)N_NODES * DFEAT * 4;
    float* h0         = (float*)ws;                          ws += (long)N_NODES * DFEAT * 4;
    float* h1         = (float*)ws;

    // ---- CSR build ----
    hipMemsetAsync(cnt, 0, 50176 * sizeof(int), stream);
    sage_hist_kernel<<<(N_EDGES + 255) / 256, 256, 0, stream>>>(dst, cnt, N_EDGES);
    sage_bsum_kernel<<<SCAN_NB, 256, 0, stream>>>(cnt, bsum, N_NODES);
    sage_bscan_kernel<<<1, 256, 0, stream>>>(bsum, SCAN_NB);
    sage_scan2_kernel<<<SCAN_NB, 256, 0, stream>>>(cnt, bsum, row_ptr, cursor, invdeg, N_NODES);
    sage_fill_kernel<<<(N_EDGES + 255) / 256, 256, 0, stream>>>(
        src, dst, cursor, sorted_src, N_EDGES);

    const int gather_blocks = (N_NODES + 1) / 2;
    const int mm_blocks = (N_NODES + 63) / 64;

    // ---- layer 0 ----
    sage_gather_kernel<<<gather_blocks, 256, 0, stream>>>(
        x, row_ptr, sorted_src, invdeg, mean, N_NODES);
    sage_mm_kernel<128, true><<<mm_blocks, 256, 0, stream>>>(
        x, mean, Ws0, Wn0, b0, h0, N_NODES);

    // ---- layer 1 ----
    sage_gather_kernel<<<gather_blocks, 256, 0, stream>>>(
        h0, row_ptr, sorted_src, invdeg, mean, N_NODES);
    sage_mm_kernel<128, true><<<mm_blocks, 256, 0, stream>>>(
        h0, mean, Ws1, Wn1, b1, h1, N_NODES);

    // ---- layer 2 ----
    sage_gather_kernel<<<gather_blocks, 256, 0, stream>>>(
        h1, row_ptr, sorted_src, invdeg, mean, N_NODES);
    sage_mm_kernel<64, false><<<mm_blocks, 256, 0, stream>>>(
        h1, mean, Ws2, Wn2, b2, out, N_NODES);
}

// Round 4
// 408.034 us; speedup vs baseline: 2.7039x; 1.2280x over previous
//
#include <hip/hip_runtime.h>

#define N_NODES 50000
#define N_EDGES 600000
#define DFEAT   128
#define SCAN_NB ((N_NODES + 255) / 256)   // 196 blocks

typedef __attribute__((ext_vector_type(8))) short short8;
typedef __attribute__((ext_vector_type(4))) float floatx4;

// ---------------- CSR build step 1: int histogram of dst ----------------
__global__ void sage_hist_kernel(const int* __restrict__ dst, int* __restrict__ cnt, int nE) {
    int e = blockIdx.x * blockDim.x + threadIdx.x;
    if (e < nE) atomicAdd(&cnt[dst[e]], 1);
}

// ---------------- CSR build step 2a: per-block sums ----------------
__global__ __launch_bounds__(256) void sage_bsum_kernel(
        const int* __restrict__ cnt, int* __restrict__ bsum, int n) {
    int i = blockIdx.x * 256 + threadIdx.x;
    int v = (i < n) ? cnt[i] : 0;
    #pragma unroll
    for (int off = 32; off > 0; off >>= 1) v += __shfl_down(v, off, 64);
    __shared__ int ws[4];
    if ((threadIdx.x & 63) == 0) ws[threadIdx.x >> 6] = v;
    __syncthreads();
    if (threadIdx.x == 0) bsum[blockIdx.x] = ws[0] + ws[1] + ws[2] + ws[3];
}

// ---------------- CSR build step 2b: exclusive scan of block sums ----------------
__global__ __launch_bounds__(256) void sage_bscan_kernel(int* __restrict__ bsum, int nb) {
    int t = threadIdx.x;
    int v = (t < nb) ? bsum[t] : 0;
    int lane = t & 63, wid = t >> 6;
    int incl = v;
    #pragma unroll
    for (int off = 1; off < 64; off <<= 1) {
        int y = __shfl_up(incl, off, 64);
        if (lane >= off) incl += y;
    }
    __shared__ int ws[4];
    if (lane == 63) ws[wid] = incl;
    __syncthreads();
    int wpre = 0;
    for (int w = 0; w < wid; w++) wpre += ws[w];
    if (t < nb) bsum[t] = wpre + incl - v;   // exclusive
}

// ---------------- CSR build step 2c: per-block scan + offset ----------------
__global__ __launch_bounds__(256) void sage_scan2_kernel(
        const int* __restrict__ cnt, const int* __restrict__ bscan,
        int* __restrict__ row_ptr, int* __restrict__ cursor,
        float* __restrict__ invdeg, int n) {
    int i = blockIdx.x * 256 + threadIdx.x;
    int v = (i < n) ? cnt[i] : 0;
    int lane = threadIdx.x & 63, wid = threadIdx.x >> 6;
    int incl = v;
    #pragma unroll
    for (int off = 1; off < 64; off <<= 1) {
        int y = __shfl_up(incl, off, 64);
        if (lane >= off) incl += y;
    }
    __shared__ int ws[4];
    if (lane == 63) ws[wid] = incl;
    __syncthreads();
    int wpre = 0;
    for (int w = 0; w < wid; w++) wpre += ws[w];
    int excl = bscan[blockIdx.x] + wpre + incl - v;
    if (i < n) {
        row_ptr[i] = excl;
        cursor[i]  = excl;
        invdeg[i]  = 1.0f / fmaxf((float)v, 1.0f);
    }
    if (i == n - 1) row_ptr[n] = excl + v;
}

// ---------------- CSR build step 3: fill sorted_src via cursor ----------------
__global__ void sage_fill_kernel(const int* __restrict__ src, const int* __restrict__ dst,
                                 int* __restrict__ cursor, int* __restrict__ sorted_src, int nE) {
    int e = blockIdx.x * blockDim.x + threadIdx.x;
    if (e < nE) {
        int p = atomicAdd(&cursor[dst[e]], 1);
        sorted_src[p] = src[e];
    }
}

// ---------------- pull-based mean aggregation ----------------
__global__ __launch_bounds__(256) void sage_gather_kernel(
        const float* __restrict__ h, const int* __restrict__ row_ptr,
        const int* __restrict__ sorted_src, const float* __restrict__ invdeg,
        float* __restrict__ mean, int nNodes)
{
    int node = blockIdx.x * 2 + (threadIdx.x >> 7);
    int f = threadIdx.x & 127;
    if (node >= nNodes) return;
    const int beg = row_ptr[node];
    const int end = row_ptr[node + 1];
    float a0 = 0.f, a1 = 0.f, a2 = 0.f, a3 = 0.f;
    int e = beg;
    for (; e + 4 <= end; e += 4) {
        int s0 = sorted_src[e];
        int s1 = sorted_src[e + 1];
        int s2 = sorted_src[e + 2];
        int s3 = sorted_src[e + 3];
        a0 += h[(long)s0 * DFEAT + f];
        a1 += h[(long)s1 * DFEAT + f];
        a2 += h[(long)s2 * DFEAT + f];
        a3 += h[(long)s3 * DFEAT + f];
    }
    for (; e < end; e++) a0 += h[(long)sorted_src[e] * DFEAT + f];
    mean[(long)node * DFEAT + f] = (a0 + a1 + a2 + a3) * invdeg[node];
}

// ---------------- W prep: split fp32 -> bf16 hi/lo, swizzle to MFMA B-frag order ----
// K=256 (Ws rows 0..127, Wn rows 128..255), NT = N/16, KT = 8 (k-tiles of 32).
// Frag storage: ((kt*NT + nt)*64 + lane)*8 + j  where element is
//   W[k = kt*32 + (lane>>4)*8 + j][n = nt*16 + (lane&15)]
__global__ __launch_bounds__(64) void sage_wprep_kernel(
        const float* __restrict__ Ws, const float* __restrict__ Wn,
        unsigned short* __restrict__ Whi, unsigned short* __restrict__ Wlo, int N) {
    int NT = N / 16;
    int fid = blockIdx.x;            // kt*NT + nt
    int kt = fid / NT, nt = fid % NT;
    int lane = threadIdx.x;
    int kbase = kt * 32 + (lane >> 4) * 8;
    int n = nt * 16 + (lane & 15);
    long base = ((long)fid * 64 + lane) * 8;
    #pragma unroll
    for (int j = 0; j < 8; j++) {
        int k = kbase + j;
        float w = (k < 128) ? Ws[k * N + n] : Wn[(k - 128) * N + n];
        unsigned b = __float_as_uint(w);
        unsigned hib = b & 0xFFFF0000u;
        float lo = w - __uint_as_float(hib);
        Whi[base + j] = (unsigned short)(b >> 16);
        Wlo[base + j] = (unsigned short)(__float_as_uint(lo) >> 16);
    }
}

// ---------------- MFMA bf16-split dual-matmul + bias + relu ----------------
// One wave (64-thread block) computes 32 rows x N cols.
// C = A@W with A = [h | mean] (K=256), via 3-term bf16 split:
//   acc += Ahi*Whi + Alo*Whi + Ahi*Wlo   (drops lo*lo ~ 2^-16 relative)
template<int NT, bool RELU>
__global__ __launch_bounds__(64) void sage_mm_mfma_kernel(
        const float* __restrict__ h, const float* __restrict__ mean,
        const unsigned short* __restrict__ Whi, const unsigned short* __restrict__ Wlo,
        const float* __restrict__ bias, float* __restrict__ out, int M)
{
    constexpr int N = NT * 16;
    const int lane = threadIdx.x;
    const int q    = lane >> 4;      // quad 0..3
    const int l16  = lane & 15;
    const int rowbase = blockIdx.x * 32;

    floatx4 acc[2][NT];
    #pragma unroll
    for (int mt = 0; mt < 2; mt++)
        #pragma unroll
        for (int nt = 0; nt < NT; nt++)
            acc[mt][nt] = (floatx4){0.f, 0.f, 0.f, 0.f};

    // A rows for this lane (clamped; invalid rows masked at store)
    int r0 = rowbase + l16;       if (r0 >= M) r0 = M - 1;
    int r1 = rowbase + 16 + l16;  if (r1 >= M) r1 = M - 1;

    #pragma unroll 2
    for (int kt = 0; kt < 8; kt++) {
        const float* srcb = (kt < 4) ? h : mean;
        const int koff = (kt & 3) * 32 + q * 8;

        union { short8 v; unsigned u[4]; } ahi[2], alo[2];
        #pragma unroll
        for (int mt = 0; mt < 2; mt++) {
            const float* p = srcb + (long)(mt == 0 ? r0 : r1) * DFEAT + koff;
            float4 x0 = *(const float4*)p;
            float4 x1 = *(const float4*)(p + 4);
            float xs[8] = {x0.x, x0.y, x0.z, x0.w, x1.x, x1.y, x1.z, x1.w};
            #pragma unroll
            for (int pr = 0; pr < 4; pr++) {
                unsigned b0 = __float_as_uint(xs[2 * pr]);
                unsigned b1 = __float_as_uint(xs[2 * pr + 1]);
                unsigned h0b = b0 & 0xFFFF0000u;
                unsigned h1b = b1 & 0xFFFF0000u;
                ahi[mt].u[pr] = (b0 >> 16) | h1b;
                float l0 = xs[2 * pr]     - __uint_as_float(h0b);
                float l1 = xs[2 * pr + 1] - __uint_as_float(h1b);
                alo[mt].u[pr] = (__float_as_uint(l0) >> 16) |
                                (__float_as_uint(l1) & 0xFFFF0000u);
            }
        }

        #pragma unroll
        for (int nt = 0; nt < NT; nt++) {
            long fb = ((long)(kt * NT + nt) * 64 + lane) * 8;
            short8 bhi = *(const short8*)(Whi + fb);
            short8 blo = *(const short8*)(Wlo + fb);
            #pragma unroll
            for (int mt = 0; mt < 2; mt++) {
                acc[mt][nt] = __builtin_amdgcn_mfma_f32_16x16x32_bf16(ahi[mt].v, bhi, acc[mt][nt], 0, 0, 0);
                acc[mt][nt] = __builtin_amdgcn_mfma_f32_16x16x32_bf16(alo[mt].v, bhi, acc[mt][nt], 0, 0, 0);
                acc[mt][nt] = __builtin_amdgcn_mfma_f32_16x16x32_bf16(ahi[mt].v, blo, acc[mt][nt], 0, 0, 0);
            }
        }
    }

    // epilogue: C layout col = lane&15, row = q*4 + reg
    #pragma unroll
    for (int nt = 0; nt < NT; nt++) {
        float bv = bias[nt * 16 + l16];
        #pragma unroll
        for (int mt = 0; mt < 2; mt++) {
            #pragma unroll
            for (int reg = 0; reg < 4; reg++) {
                int grow = rowbase + mt * 16 + q * 4 + reg;
                if (grow < M) {
                    float v = acc[mt][nt][reg] + bv;
                    if (RELU) v = fmaxf(v, 0.f);
                    out[(long)grow * N + nt * 16 + l16] = v;
                }
            }
        }
    }
}

extern "C" void kernel_launch(void* const* d_in, const int* in_sizes, int n_in,
                              void* d_out, int out_size, void* d_ws, size_t ws_size,
                              hipStream_t stream) {
    const float* x   = (const float*)d_in[0];
    const int*   ei  = (const int*)d_in[1];
    const float* Ws0 = (const float*)d_in[2];
    const float* Wn0 = (const float*)d_in[3];
    const float* b0  = (const float*)d_in[4];
    const float* Ws1 = (const float*)d_in[5];
    const float* Wn1 = (const float*)d_in[6];
    const float* b1  = (const float*)d_in[7];
    const float* Ws2 = (const float*)d_in[8];
    const float* Wn2 = (const float*)d_in[9];
    const float* b2  = (const float*)d_in[10];
    float* out = (float*)d_out;

    const int* src = ei;
    const int* dst = ei + N_EDGES;

    // ---- workspace layout ----
    char* ws = (char*)d_ws;
    float* invdeg     = (float*)ws;   ws += 50176 * 4;
    int*   cnt        = (int*)ws;     ws += 50176 * 4;
    int*   row_ptr    = (int*)ws;     ws += 50432 * 4;
    int*   cursor     = (int*)ws;     ws += 50432 * 4;
    int*   bsum       = (int*)ws;     ws += 256 * 4;
    int*   sorted_src = (int*)ws;     ws += 600064 * 4;
    unsigned short* Whi0 = (unsigned short*)ws; ws += 8 * 8 * 64 * 8 * 2;   // 64 KB
    unsigned short* Wlo0 = (unsigned short*)ws; ws += 8 * 8 * 64 * 8 * 2;
    unsigned short* Whi1 = (unsigned short*)ws; ws += 8 * 8 * 64 * 8 * 2;
    unsigned short* Wlo1 = (unsigned short*)ws; ws += 8 * 8 * 64 * 8 * 2;
    unsigned short* Whi2 = (unsigned short*)ws; ws += 8 * 4 * 64 * 8 * 2;   // 32 KB
    unsigned short* Wlo2 = (unsigned short*)ws; ws += 8 * 4 * 64 * 8 * 2;
    float* mean       = (float*)ws;   ws += (long)N_NODES * DFEAT * 4;
    float* h0         = (float*)ws;   ws += (long)N_NODES * DFEAT * 4;
    float* h1         = (float*)ws;

    // ---- CSR build ----
    hipMemsetAsync(cnt, 0, 50176 * sizeof(int), stream);
    sage_hist_kernel<<<(N_EDGES + 255) / 256, 256, 0, stream>>>(dst, cnt, N_EDGES);
    sage_bsum_kernel<<<SCAN_NB, 256, 0, stream>>>(cnt, bsum, N_NODES);
    sage_bscan_kernel<<<1, 256, 0, stream>>>(bsum, SCAN_NB);
    sage_scan2_kernel<<<SCAN_NB, 256, 0, stream>>>(cnt, bsum, row_ptr, cursor, invdeg, N_NODES);
    sage_fill_kernel<<<(N_EDGES + 255) / 256, 256, 0, stream>>>(
        src, dst, cursor, sorted_src, N_EDGES);

    // ---- weight prep (cheap; overlaps CSR work in-stream) ----
    sage_wprep_kernel<<<64, 64, 0, stream>>>(Ws0, Wn0, Whi0, Wlo0, 128);
    sage_wprep_kernel<<<64, 64, 0, stream>>>(Ws1, Wn1, Whi1, Wlo1, 128);
    sage_wprep_kernel<<<32, 64, 0, stream>>>(Ws2, Wn2, Whi2, Wlo2, 64);

    const int gather_blocks = (N_NODES + 1) / 2;
    const int mm_blocks = (N_NODES + 31) / 32;   // 1563 single-wave blocks

    // ---- layer 0 ----
    sage_gather_kernel<<<gather_blocks, 256, 0, stream>>>(
        x, row_ptr, sorted_src, invdeg, mean, N_NODES);
    sage_mm_mfma_kernel<8, true><<<mm_blocks, 64, 0, stream>>>(
        x, mean, Whi0, Wlo0, b0, h0, N_NODES);

    // ---- layer 1 ----
    sage_gather_kernel<<<gather_blocks, 256, 0, stream>>>(
        h0, row_ptr, sorted_src, invdeg, mean, N_NODES);
    sage_mm_mfma_kernel<8, true><<<mm_blocks, 64, 0, stream>>>(
        h0, mean, Whi1, Wlo1, b1, h1, N_NODES);

    // ---- layer 2 ----
    sage_gather_kernel<<<gather_blocks, 256, 0, stream>>>(
        h1, row_ptr, sorted_src, invdeg, mean, N_NODES);
    sage_mm_mfma_kernel<4, false><<<mm_blocks, 64, 0, stream>>>(
        h1, mean, Whi2, Wlo2, b2, out, N_NODES);
}